// Round 4
// baseline (4185.436 us; speedup 1.0000x reference)
//
#include <hip/hip_runtime.h>
#include <hip/hip_bf16.h>

#define Tn   8192
#define Dn   1024
#define FFn  4096
#define En   8
#define CAPn 2560
#define MAXROWS 16384  // <= K*T total kept slots

typedef __attribute__((ext_vector_type(8))) short bf16x8;
typedef __attribute__((ext_vector_type(4))) float f32x4;

__device__ inline ushort f2bf(float f) {            // RNE fp32->bf16 bits
  unsigned u = __float_as_uint(f);
  return (ushort)((u + 0x7fff + ((u >> 16) & 1)) >> 16);
}
__device__ inline float bf2f(ushort b) { return __uint_as_float(((unsigned)b) << 16); }

// ---------------------------------------------------------------- gating ----
__global__ __launch_bounds__(256) void gate_kernel(
    const float* __restrict__ x, const float* __restrict__ gw,
    const float* __restrict__ gb, int* __restrict__ tidx,
    float* __restrict__ tprob) {
  __shared__ float sgw[En * Dn];  // 32 KB
  for (int i = threadIdx.x; i < En * Dn / 4; i += 256)
    ((float4*)sgw)[i] = ((const float4*)gw)[i];
  __syncthreads();
  const int wave = threadIdx.x >> 6, lane = threadIdx.x & 63;
  const int t = blockIdx.x * 4 + wave;
  float acc[En];
#pragma unroll
  for (int e = 0; e < En; ++e) acc[e] = 0.f;
  const float4* xr = (const float4*)(x + (size_t)t * Dn);
#pragma unroll
  for (int it = 0; it < Dn / 4 / 64; ++it) {
    const float4 xv = xr[it * 64 + lane];
#pragma unroll
    for (int e = 0; e < En; ++e) {
      const float4 wv = ((const float4*)(sgw + e * Dn))[it * 64 + lane];
      acc[e] += xv.x * wv.x + xv.y * wv.y + xv.z * wv.z + xv.w * wv.w;
    }
  }
#pragma unroll
  for (int e = 0; e < En; ++e)
#pragma unroll
    for (int off = 32; off; off >>= 1) acc[e] += __shfl_xor(acc[e], off, 64);
  if (lane == 0) {
    float lg[En], mx = -1e30f;
#pragma unroll
    for (int e = 0; e < En; ++e) { lg[e] = acc[e] + gb[e]; mx = fmaxf(mx, lg[e]); }
    float ex[En], s = 0.f;
#pragma unroll
    for (int e = 0; e < En; ++e) { ex[e] = expf(lg[e] - mx); s += ex[e]; }
    int i0 = 0;
#pragma unroll
    for (int e = 1; e < En; ++e) if (ex[e] > ex[i0]) i0 = e;
    int i1 = (i0 == 0) ? 1 : 0;
#pragma unroll
    for (int e = 0; e < En; ++e) if (e != i0 && ex[e] > ex[i1]) i1 = e;
    const float inv = 1.f / s;
    tidx[t * 2 + 0] = i0;  tidx[t * 2 + 1] = i1;
    tprob[t * 2 + 0] = ex[i0] * inv;  tprob[t * 2 + 1] = ex[i1] * inv;
  }
}

// ------------------------------------------------------- routing (1 block) --
__global__ __launch_bounds__(1024) void route_kernel(
    const int* __restrict__ tidx, const float* __restrict__ tprob,
    int* __restrict__ slot_token, float* __restrict__ slot_w,
    int* __restrict__ meta) {
  __shared__ int sc[1024][16];  // 64 KB
  const int tid = threadIdx.x;
  int cnt[16];
#pragma unroll
  for (int j = 0; j < 16; ++j) cnt[j] = 0;
  int eb[8][2];
#pragma unroll
  for (int i = 0; i < 8; ++i) {
    const int t = tid * 8 + i;
    eb[i][0] = tidx[t * 2 + 0];
    eb[i][1] = tidx[t * 2 + 1];
#pragma unroll
    for (int e = 0; e < 8; ++e) {
      cnt[e]     += (eb[i][0] == e);
      cnt[8 + e] += (eb[i][1] == e);
    }
  }
  int own[16];
#pragma unroll
  for (int j = 0; j < 16; ++j) { own[j] = cnt[j]; sc[tid][j] = cnt[j]; }
  __syncthreads();
  for (int off = 1; off < 1024; off <<= 1) {
    int nb[16];
    if (tid >= off) {
#pragma unroll
      for (int j = 0; j < 16; ++j) nb[j] = sc[tid - off][j];
    } else {
#pragma unroll
      for (int j = 0; j < 16; ++j) nb[j] = 0;
    }
    __syncthreads();
#pragma unroll
    for (int j = 0; j < 16; ++j) sc[tid][j] += nb[j];
    __syncthreads();
  }
  int tot[16], exc[16];
#pragma unroll
  for (int j = 0; j < 16; ++j) {
    tot[j] = sc[1023][j];
    exc[j] = sc[tid][j] - own[j];
  }
  __syncthreads();
  if (tid == 0) {
    int b = 0;
#pragma unroll
    for (int e = 0; e < 8; ++e) {
      const int c0 = min(tot[e], CAPn);
      const int c1 = min(tot[8 + e], CAPn);
      sc[0][e] = b;
      sc[1][e] = c0;
      meta[e] = c0 + c1;
      meta[8 + e] = b;
      b += c0 + c1;
    }
  }
  __syncthreads();
  int pos[16];
#pragma unroll
  for (int j = 0; j < 16; ++j) pos[j] = exc[j];
#pragma unroll
  for (int i = 0; i < 8; ++i) {
    const int t = tid * 8 + i;
#pragma unroll
    for (int c = 0; c < 2; ++c) {
      const int e = eb[i][c];
      const int jt = c * 8 + e;
      int p = 0;
#pragma unroll
      for (int j = 0; j < 16; ++j) p = (j == jt) ? pos[j] : p;
#pragma unroll
      for (int j = 0; j < 16; ++j) pos[j] += (j == jt) ? 1 : 0;
      if (p < CAPn) {
        const int slot = sc[0][e] + ((c == 1) ? sc[1][e] : 0) + p;
        slot_token[slot] = t;
        slot_w[slot] = tprob[t * 2 + c];
      }
    }
  }
}

// ---------------------------------------------- split h -> bf16 hi/lo planes
__global__ __launch_bounds__(256) void convert_x_kernel(
    const float* __restrict__ x, ushort* __restrict__ xh, ushort* __restrict__ xl) {
  const size_t i = (size_t)(blockIdx.x * 256 + threadIdx.x) * 8;
  if (i >= (size_t)Tn * Dn) return;
  const float4 a = ((const float4*)(x + i))[0];
  const float4 b = ((const float4*)(x + i))[1];
  const float v[8] = {a.x, a.y, a.z, a.w, b.x, b.y, b.z, b.w};
  union { ushort u[8]; uint4 q; } H, L;
#pragma unroll
  for (int j = 0; j < 8; ++j) {
    const ushort hb = f2bf(v[j]);
    H.u[j] = hb;
    L.u[j] = f2bf(v[j] - bf2f(hb));
  }
  *(uint4*)(xh + i) = H.q;
  *(uint4*)(xl + i) = L.q;
}

// ------------------- transpose W[k][n] -> Wt[n][k], split into hi/lo planes -
__global__ __launch_bounds__(256) void transpose_w_kernel(
    const float* __restrict__ W, ushort* __restrict__ Wth,
    ushort* __restrict__ Wtl, int K, int N) {
  __shared__ float t[64][65];
  const float* src = W + (size_t)blockIdx.z * K * N;
  const int k0 = blockIdx.y * 64, n0 = blockIdx.x * 64;
  const int tid = threadIdx.x;
#pragma unroll
  for (int i = 0; i < 4; ++i) {
    const int idx = tid + i * 256;
    const int r = idx >> 4, c = (idx & 15) * 4;
    const float4 v = *(const float4*)(src + (size_t)(k0 + r) * N + n0 + c);
    t[r][c] = v.x; t[r][c + 1] = v.y; t[r][c + 2] = v.z; t[r][c + 3] = v.w;
  }
  __syncthreads();
  const size_t pb = (size_t)blockIdx.z * N * K;
  const int n = tid >> 2, kq = (tid & 3) * 16;
  union { ushort u[8]; uint4 q; } H0, H1, L0, L1;
#pragma unroll
  for (int j = 0; j < 8; ++j) {
    float f = t[kq + j][n];
    ushort hb = f2bf(f);
    H0.u[j] = hb; L0.u[j] = f2bf(f - bf2f(hb));
    f = t[kq + 8 + j][n];
    hb = f2bf(f);
    H1.u[j] = hb; L1.u[j] = f2bf(f - bf2f(hb));
  }
  ushort* dh = Wth + pb + (size_t)(n0 + n) * K + k0 + kq;
  ushort* dl = Wtl + pb + (size_t)(n0 + n) * K + k0 + kq;
  *(uint4*)dh = H0.q;  *(uint4*)(dh + 8) = H1.q;
  *(uint4*)dl = L0.q;  *(uint4*)(dl + 8) = L1.q;
}

// -------------------------------------------------- split-bf16 MFMA GEMM ----
// GEMM==1: hmid = relu(X[token] @ W1 + b1)  (store hi/lo bf16 planes)
// GEMM==2: y[token] += w * (hmid @ W2 + b2) (fp32 atomics)
template <int GEMM>
__global__ __launch_bounds__(256) void mfma_ffn_kernel(
    const ushort* __restrict__ Ah_g, const ushort* __restrict__ Al_g,
    const ushort* __restrict__ Bh_g, const ushort* __restrict__ Bl_g,
    const float* __restrict__ bias, const int* __restrict__ slot_token,
    const float* __restrict__ slot_w, const int* __restrict__ meta,
    ushort* __restrict__ outh, ushort* __restrict__ outl,
    float* __restrict__ y) {
  constexpr int Kdim = (GEMM == 1) ? Dn : FFn;
  constexpr int Ndim = (GEMM == 1) ? FFn : Dn;
  const int e = blockIdx.z;
  const int cnt = meta[e];
  const int m0 = blockIdx.y * 128;
  if (m0 >= cnt) return;
  const int base = meta[8 + e];
  const int n0 = blockIdx.x * 128;

  __shared__ short lds[4 * 128 * 64];  // Ah | Al | Bh | Bl tiles, 64 KB
  __shared__ int srow[128];
  const int tid = threadIdx.x;
  if (tid < 128) {
    const int m = min(m0 + tid, cnt - 1);
    srow[tid] = (GEMM == 1) ? slot_token[base + m] : (base + m);
  }
  const ushort* Bh_e = Bh_g + (size_t)e * (size_t)Kdim * Ndim;
  const ushort* Bl_e = Bl_g + (size_t)e * (size_t)Kdim * Ndim;
  __syncthreads();

  const int wv = tid >> 6, ln = tid & 63;
  const int wm = (wv & 1) * 64, wn = (wv >> 1) * 64;
  const int lrow = ln & 15, kgrp = ln >> 4;

  f32x4 acc[4][4];
#pragma unroll
  for (int i = 0; i < 4; ++i)
#pragma unroll
    for (int j = 0; j < 4; ++j) acc[i][j] = (f32x4){0.f, 0.f, 0.f, 0.f};

  for (int k0 = 0; k0 < Kdim; k0 += 64) {
    __syncthreads();  // previous tile's fragment reads complete
    uint4 va[4], vb[4], vc[4], vd[4];
#pragma unroll
    for (int i = 0; i < 4; ++i) {
      const int g = tid + i * 256;
      const int r = g >> 3, kb = g & 7;
      const size_t ga = (size_t)srow[r] * Kdim + k0 + kb * 8;
      va[i] = *(const uint4*)(Ah_g + ga);
      vb[i] = *(const uint4*)(Al_g + ga);
      const size_t gb = (size_t)(n0 + r) * Kdim + k0 + kb * 8;
      vc[i] = *(const uint4*)(Bh_e + gb);
      vd[i] = *(const uint4*)(Bl_e + gb);
    }
#pragma unroll
    for (int i = 0; i < 4; ++i) {
      const int g = tid + i * 256;
      const int r = g >> 3, kb = g & 7;
      const int la = r * 64 + ((kb ^ (r & 7)) << 3);  // XOR-swizzled 16B block
      *(uint4*)(lds + 0 * 8192 + la) = va[i];
      *(uint4*)(lds + 1 * 8192 + la) = vb[i];
      *(uint4*)(lds + 2 * 8192 + la) = vc[i];
      *(uint4*)(lds + 3 * 8192 + la) = vd[i];
    }
    __syncthreads();
#pragma unroll
    for (int ks = 0; ks < 2; ++ks) {
      const int kb = ks * 4 + kgrp;
      bf16x8 ah[4], al[4], bh[4], bl[4];
#pragma unroll
      for (int f = 0; f < 4; ++f) {
        const int ra = wm + f * 16 + lrow;
        const int ia = ra * 64 + ((kb ^ (ra & 7)) << 3);
        ah[f] = *(const bf16x8*)(lds + 0 * 8192 + ia);
        al[f] = *(const bf16x8*)(lds + 1 * 8192 + ia);
        const int rb = wn + f * 16 + lrow;
        const int ib = rb * 64 + ((kb ^ (rb & 7)) << 3);
        bh[f] = *(const bf16x8*)(lds + 2 * 8192 + ib);
        bl[f] = *(const bf16x8*)(lds + 3 * 8192 + ib);
      }
#pragma unroll
      for (int fm = 0; fm < 4; ++fm)
#pragma unroll
        for (int fn = 0; fn < 4; ++fn) {
          acc[fm][fn] = __builtin_amdgcn_mfma_f32_16x16x32_bf16(ah[fm], bh[fn], acc[fm][fn], 0, 0, 0);
          acc[fm][fn] = __builtin_amdgcn_mfma_f32_16x16x32_bf16(ah[fm], bl[fn], acc[fm][fn], 0, 0, 0);
          acc[fm][fn] = __builtin_amdgcn_mfma_f32_16x16x32_bf16(al[fm], bh[fn], acc[fm][fn], 0, 0, 0);
        }
    }
  }

  float bv[4];
#pragma unroll
  for (int fn = 0; fn < 4; ++fn)
    bv[fn] = bias[(size_t)e * Ndim + n0 + wn + fn * 16 + lrow];

#pragma unroll
  for (int fm = 0; fm < 4; ++fm)
#pragma unroll
    for (int j = 0; j < 4; ++j) {
      const int m = m0 + wm + fm * 16 + kgrp * 4 + j;  // C/D: row=(lane>>4)*4+reg
      if (m < cnt) {
        if (GEMM == 1) {
          const size_t o = (size_t)(base + m) * FFn + n0 + wn;
#pragma unroll
          for (int fn = 0; fn < 4; ++fn) {
            const float v = fmaxf(acc[fm][fn][j] + bv[fn], 0.f);
            const ushort hb = f2bf(v);
            outh[o + fn * 16 + lrow] = hb;
            outl[o + fn * 16 + lrow] = f2bf(v - bf2f(hb));
          }
        } else {
          const int t = slot_token[base + m];
          const float w = slot_w[base + m];
          float* yr = y + (size_t)t * Dn + n0 + wn;
#pragma unroll
          for (int fn = 0; fn < 4; ++fn)
            atomicAdd(yr + fn * 16 + lrow, w * (acc[fm][fn][j] + bv[fn]));
        }
      }
    }
}

// ------------------------------------- fp32 fallback GEMMs (small-ws path) --
__device__ inline void load8f(const float* p, float* v) {
  const float4 a = ((const float4*)p)[0];
  const float4 b = ((const float4*)p)[1];
  v[0] = a.x; v[1] = a.y; v[2] = a.z; v[3] = a.w;
  v[4] = b.x; v[5] = b.y; v[6] = b.z; v[7] = b.w;
}
__device__ inline void load8h(const float* p, float* v) { load8f(p, v); }
__device__ inline void load8h(const __hip_bfloat16* p, float* v) {
  const uint4 r = *(const uint4*)p;
  const unsigned short* s = (const unsigned short*)&r;
#pragma unroll
  for (int j = 0; j < 8; ++j) v[j] = __uint_as_float(((unsigned)s[j]) << 16);
}
__device__ inline void storeh(float* p, float v) { *p = v; }
__device__ inline void storeh(__hip_bfloat16* p, float v) { *p = __hip_bfloat16(v); }

template <typename TH>
__global__ __launch_bounds__(256) void ffn1_kernel(
    const float* __restrict__ X, const float* __restrict__ W1,
    const float* __restrict__ b1, const int* __restrict__ slot_token,
    const int* __restrict__ meta, TH* __restrict__ hmid) {
  const int e = blockIdx.z;
  const int cnt = meta[e];
  const int m0 = blockIdx.y * 64;
  if (m0 >= cnt) return;
  const int base = meta[8 + e];
  const int n0 = blockIdx.x * 64;
  __shared__ float As[32][64];
  __shared__ float Bs[32][64];
  const int tid = threadIdx.x;
  const int arow = tid >> 2, ak0 = (tid & 3) * 8;
  const int tok = slot_token[base + min(m0 + arow, cnt - 1)];
  const float* xrow = X + (size_t)tok * Dn;
  const int bkk = tid >> 3, bc0 = (tid & 7) * 8;
  const float* wrow = W1 + (size_t)e * Dn * FFn + n0;
  const int tm = (tid >> 4) << 2, tn = (tid & 15) << 2;
  float acc[4][4] = {};
  for (int k0 = 0; k0 < Dn; k0 += 32) {
    float av[8], bv[8];
    load8f(xrow + k0 + ak0, av);
    load8f(wrow + (size_t)(k0 + bkk) * FFn + bc0, bv);
    __syncthreads();
#pragma unroll
    for (int u = 0; u < 8; ++u) As[ak0 + u][arow] = av[u];
#pragma unroll
    for (int u = 0; u < 8; ++u) Bs[bkk][bc0 + u] = bv[u];
    __syncthreads();
#pragma unroll
    for (int kk = 0; kk < 32; ++kk) {
      float a[4], b[4];
#pragma unroll
      for (int i = 0; i < 4; ++i) a[i] = As[kk][tm + i];
#pragma unroll
      for (int j = 0; j < 4; ++j) b[j] = Bs[kk][tn + j];
#pragma unroll
      for (int i = 0; i < 4; ++i)
#pragma unroll
        for (int j = 0; j < 4; ++j) acc[i][j] = fmaf(a[i], b[j], acc[i][j]);
    }
  }
  const float* bb = b1 + (size_t)e * FFn + n0;
#pragma unroll
  for (int i = 0; i < 4; ++i) {
    const int m = m0 + tm + i;
    if (m < cnt) {
      TH* hr = hmid + (size_t)(base + m) * FFn + n0 + tn;
#pragma unroll
      for (int j = 0; j < 4; ++j)
        storeh(hr + j, fmaxf(acc[i][j] + bb[tn + j], 0.f));
    }
  }
}

template <typename TH>
__global__ __launch_bounds__(256) void ffn2_kernel(
    const TH* __restrict__ hmid, const float* __restrict__ W2,
    const float* __restrict__ b2, const int* __restrict__ slot_token,
    const float* __restrict__ slot_w, const int* __restrict__ meta,
    float* __restrict__ y) {
  const int e = blockIdx.z;
  const int cnt = meta[e];
  const int m0 = blockIdx.y * 64;
  if (m0 >= cnt) return;
  const int base = meta[8 + e];
  const int n0 = blockIdx.x * 64;
  __shared__ float As[32][64];
  __shared__ float Bs[32][64];
  const int tid = threadIdx.x;
  const int arow = tid >> 2, ak0 = (tid & 3) * 8;
  const TH* hrow = hmid + (size_t)(base + min(m0 + arow, cnt - 1)) * FFn;
  const int bkk = tid >> 3, bc0 = (tid & 7) * 8;
  const float* wrow = W2 + (size_t)e * FFn * Dn + n0;
  const int tm = (tid >> 4) << 2, tn = (tid & 15) << 2;
  float acc[4][4] = {};
  for (int k0 = 0; k0 < FFn; k0 += 32) {
    float av[8], bv[8];
    load8h(hrow + k0 + ak0, av);
    load8f(wrow + (size_t)(k0 + bkk) * Dn + bc0, bv);
    __syncthreads();
#pragma unroll
    for (int u = 0; u < 8; ++u) As[ak0 + u][arow] = av[u];
#pragma unroll
    for (int u = 0; u < 8; ++u) Bs[bkk][bc0 + u] = bv[u];
    __syncthreads();
#pragma unroll
    for (int kk = 0; kk < 32; ++kk) {
      float a[4], b[4];
#pragma unroll
      for (int i = 0; i < 4; ++i) a[i] = As[kk][tm + i];
#pragma unroll
      for (int j = 0; j < 4; ++j) b[j] = Bs[kk][tn + j];
#pragma unroll
      for (int i = 0; i < 4; ++i)
#pragma unroll
        for (int j = 0; j < 4; ++j) acc[i][j] = fmaf(a[i], b[j], acc[i][j]);
    }
  }
  const float* bb = b2 + (size_t)e * Dn + n0;
#pragma unroll
  for (int i = 0; i < 4; ++i) {
    const int m = m0 + tm + i;
    if (m < cnt) {
      const int t = slot_token[base + m];
      const float w = slot_w[base + m];
      float* yr = y + (size_t)t * Dn + n0 + tn;
#pragma unroll
      for (int j = 0; j < 4; ++j)
        atomicAdd(&yr[j], w * (acc[i][j] + bb[tn + j]));
    }
  }
}

// ---------------------------------------------------------------- launch ----
extern "C" void kernel_launch(void* const* d_in, const int* in_sizes, int n_in,
                              void* d_out, int out_size, void* d_ws, size_t ws_size,
                              hipStream_t stream) {
  const float* h  = (const float*)d_in[0];
  const float* gw = (const float*)d_in[1];
  const float* gb = (const float*)d_in[2];
  const float* W1 = (const float*)d_in[3];
  const float* b1 = (const float*)d_in[4];
  const float* W2 = (const float*)d_in[5];
  const float* b2 = (const float*)d_in[6];
  float* y = (float*)d_out;

  char* ws = (char*)d_ws;
  size_t off = 0;
  auto carve = [&](size_t bytes) -> char* {
    char* p = ws + off;
    off = (off + bytes + 255) & ~(size_t)255;
    return p;
  };
  int*    tidx       = (int*)carve((size_t)Tn * 2 * 4);
  float*  tprob      = (float*)carve((size_t)Tn * 2 * 4);
  int*    slot_token = (int*)carve((size_t)MAXROWS * 4);
  float*  slot_w     = (float*)carve((size_t)MAXROWS * 4);
  int*    meta       = (int*)carve(256);
  const size_t small_end = off;

  hipMemsetAsync(d_out, 0, (size_t)Tn * Dn * sizeof(float), stream);
  gate_kernel<<<Tn / 4, 256, 0, stream>>>(h, gw, gb, tidx, tprob);
  route_kernel<<<1, 1024, 0, stream>>>(tidx, tprob, slot_token, slot_w, meta);

  // ---- MFMA split-bf16 path ----
  const size_t xplane = (size_t)Tn * Dn * 2;           // 16.75 MB
  const size_t wplane = (size_t)En * Dn * FFn * 2;     // 67 MB
  const size_t hplane = (size_t)MAXROWS * FFn * 2;     // 134 MB
  const size_t need_mfma = small_end + 2 * xplane + 4 * wplane + 2 * hplane + 4096;

  if (ws_size >= need_mfma) {
    ushort* Xh   = (ushort*)carve(xplane);
    ushort* Xl   = (ushort*)carve(xplane);
    ushort* W1th = (ushort*)carve(wplane);
    ushort* W1tl = (ushort*)carve(wplane);
    ushort* W2th = (ushort*)carve(wplane);
    ushort* W2tl = (ushort*)carve(wplane);
    ushort* Hh   = (ushort*)carve(hplane);
    ushort* Hl   = (ushort*)carve(hplane);

    convert_x_kernel<<<(Tn * Dn / 8 + 255) / 256, 256, 0, stream>>>(h, Xh, Xl);
    transpose_w_kernel<<<dim3(FFn / 64, Dn / 64, En), 256, 0, stream>>>(W1, W1th, W1tl, Dn, FFn);
    transpose_w_kernel<<<dim3(Dn / 64, FFn / 64, En), 256, 0, stream>>>(W2, W2th, W2tl, FFn, Dn);

    const dim3 g1(FFn / 128, (2 * CAPn) / 128, En);   // (32, 40, 8)
    const dim3 g2(Dn / 128, (2 * CAPn) / 128, En);    // (8, 40, 8)
    mfma_ffn_kernel<1><<<g1, 256, 0, stream>>>(Xh, Xl, W1th, W1tl, b1,
                                               slot_token, slot_w, meta, Hh, Hl, nullptr);
    mfma_ffn_kernel<2><<<g2, 256, 0, stream>>>(Hh, Hl, W2th, W2tl, b2,
                                               slot_token, slot_w, meta, nullptr, nullptr, y);
    return;
  }

  // ---- fp32 fallback path ----
  const size_t need_f32 = small_end + (size_t)MAXROWS * FFn * sizeof(float);
  const dim3 f1(FFn / 64, (2 * CAPn + 63) / 64, En);
  const dim3 f2(Dn / 64, (2 * CAPn + 63) / 64, En);
  if (ws_size >= need_f32) {
    float* hmid = (float*)(ws + small_end);
    ffn1_kernel<float><<<f1, 256, 0, stream>>>(h, W1, b1, slot_token, meta, hmid);
    ffn2_kernel<float><<<f2, 256, 0, stream>>>(hmid, W2, b2, slot_token, slot_w, meta, y);
  } else {
    __hip_bfloat16* hmid = (__hip_bfloat16*)(ws + small_end);
    ffn1_kernel<__hip_bfloat16><<<f1, 256, 0, stream>>>(h, W1, b1, slot_token, meta, hmid);
    ffn2_kernel<__hip_bfloat16><<<f2, 256, 0, stream>>>(hmid, W2, b2, slot_token, slot_w, meta, y);
  }
}

// Round 5
// 1227.948 us; speedup vs baseline: 3.4085x; 3.4085x over previous
//
#include <hip/hip_runtime.h>
#include <hip/hip_bf16.h>

#define Tn   8192
#define Dn   1024
#define FFn  4096
#define En   8
#define CAPn 2560
#define MAXROWS 16384  // <= K*T total kept slots

typedef __attribute__((ext_vector_type(8))) short bf16x8;
typedef __attribute__((ext_vector_type(4))) float f32x4;

__device__ inline ushort f2bf(float f) {            // RNE fp32->bf16 bits
  unsigned u = __float_as_uint(f);
  return (ushort)((u + 0x7fff + ((u >> 16) & 1)) >> 16);
}
__device__ inline float bf2f(ushort b) { return __uint_as_float(((unsigned)b) << 16); }

// ---------------------------------------------------------------- gating ----
__global__ __launch_bounds__(256) void gate_kernel(
    const float* __restrict__ x, const float* __restrict__ gw,
    const float* __restrict__ gb, int* __restrict__ tidx,
    float* __restrict__ tprob) {
  __shared__ float sgw[En * Dn];  // 32 KB
  for (int i = threadIdx.x; i < En * Dn / 4; i += 256)
    ((float4*)sgw)[i] = ((const float4*)gw)[i];
  __syncthreads();
  const int wave = threadIdx.x >> 6, lane = threadIdx.x & 63;
  const int t = blockIdx.x * 4 + wave;
  float acc[En];
#pragma unroll
  for (int e = 0; e < En; ++e) acc[e] = 0.f;
  const float4* xr = (const float4*)(x + (size_t)t * Dn);
#pragma unroll
  for (int it = 0; it < Dn / 4 / 64; ++it) {
    const float4 xv = xr[it * 64 + lane];
#pragma unroll
    for (int e = 0; e < En; ++e) {
      const float4 wv = ((const float4*)(sgw + e * Dn))[it * 64 + lane];
      acc[e] += xv.x * wv.x + xv.y * wv.y + xv.z * wv.z + xv.w * wv.w;
    }
  }
#pragma unroll
  for (int e = 0; e < En; ++e)
#pragma unroll
    for (int off = 32; off; off >>= 1) acc[e] += __shfl_xor(acc[e], off, 64);
  if (lane == 0) {
    float lg[En], mx = -1e30f;
#pragma unroll
    for (int e = 0; e < En; ++e) { lg[e] = acc[e] + gb[e]; mx = fmaxf(mx, lg[e]); }
    float ex[En], s = 0.f;
#pragma unroll
    for (int e = 0; e < En; ++e) { ex[e] = expf(lg[e] - mx); s += ex[e]; }
    int i0 = 0;
#pragma unroll
    for (int e = 1; e < En; ++e) if (ex[e] > ex[i0]) i0 = e;
    int i1 = (i0 == 0) ? 1 : 0;
#pragma unroll
    for (int e = 0; e < En; ++e) if (e != i0 && ex[e] > ex[i1]) i1 = e;
    const float inv = 1.f / s;
    tidx[t * 2 + 0] = i0;  tidx[t * 2 + 1] = i1;
    tprob[t * 2 + 0] = ex[i0] * inv;  tprob[t * 2 + 1] = ex[i1] * inv;
  }
}

// ------------------------------------------------------- routing (1 block) --
__global__ __launch_bounds__(1024) void route_kernel(
    const int* __restrict__ tidx, const float* __restrict__ tprob,
    int* __restrict__ slot_token, float* __restrict__ slot_w,
    int* __restrict__ meta) {
  __shared__ int sc[1024][16];  // 64 KB
  const int tid = threadIdx.x;
  int cnt[16];
#pragma unroll
  for (int j = 0; j < 16; ++j) cnt[j] = 0;
  int eb[8][2];
#pragma unroll
  for (int i = 0; i < 8; ++i) {
    const int t = tid * 8 + i;
    eb[i][0] = tidx[t * 2 + 0];
    eb[i][1] = tidx[t * 2 + 1];
#pragma unroll
    for (int e = 0; e < 8; ++e) {
      cnt[e]     += (eb[i][0] == e);
      cnt[8 + e] += (eb[i][1] == e);
    }
  }
  int own[16];
#pragma unroll
  for (int j = 0; j < 16; ++j) { own[j] = cnt[j]; sc[tid][j] = cnt[j]; }
  __syncthreads();
  for (int off = 1; off < 1024; off <<= 1) {
    int nb[16];
    if (tid >= off) {
#pragma unroll
      for (int j = 0; j < 16; ++j) nb[j] = sc[tid - off][j];
    } else {
#pragma unroll
      for (int j = 0; j < 16; ++j) nb[j] = 0;
    }
    __syncthreads();
#pragma unroll
    for (int j = 0; j < 16; ++j) sc[tid][j] += nb[j];
    __syncthreads();
  }
  int tot[16], exc[16];
#pragma unroll
  for (int j = 0; j < 16; ++j) {
    tot[j] = sc[1023][j];
    exc[j] = sc[tid][j] - own[j];
  }
  __syncthreads();
  if (tid == 0) {
    int b = 0;
#pragma unroll
    for (int e = 0; e < 8; ++e) {
      const int c0 = min(tot[e], CAPn);
      const int c1 = min(tot[8 + e], CAPn);
      sc[0][e] = b;
      sc[1][e] = c0;
      meta[e] = c0 + c1;
      meta[8 + e] = b;
      b += c0 + c1;
    }
  }
  __syncthreads();
  int pos[16];
#pragma unroll
  for (int j = 0; j < 16; ++j) pos[j] = exc[j];
#pragma unroll
  for (int i = 0; i < 8; ++i) {
    const int t = tid * 8 + i;
#pragma unroll
    for (int c = 0; c < 2; ++c) {
      const int e = eb[i][c];
      const int jt = c * 8 + e;
      int p = 0;
#pragma unroll
      for (int j = 0; j < 16; ++j) p = (j == jt) ? pos[j] : p;
#pragma unroll
      for (int j = 0; j < 16; ++j) pos[j] += (j == jt) ? 1 : 0;
      if (p < CAPn) {
        const int slot = sc[0][e] + ((c == 1) ? sc[1][e] : 0) + p;
        slot_token[slot] = t;
        slot_w[slot] = tprob[t * 2 + c];
      }
    }
  }
}

// --------------------------------------------- split-bf16 MFMA FFN GEMMs ----
// GEMM==1: H[slot] = relu(X[token[slot]] @ W1[e] + b1[e])   (bf16 out)
// GEMM==2: y[token] += w * (H[slot] @ W2[e] + b2[e])         (fp32 atomics)
// A and B converted to split-bf16 during LDS staging; W transposed in-flight.
// LDS planes layout: [row][4 blocks of 8 bf16], block XOR-swizzled by
// blk' = blk ^ ((row>>1)&3)  -> 2-way (free) bank access on write and read.
template <int GEMM>
__global__ __launch_bounds__(256) void mfma_ffn(
    const float* __restrict__ Xf, const ushort* __restrict__ Hb,
    const float* __restrict__ Wg, const float* __restrict__ bias,
    const int* __restrict__ slot_token, const float* __restrict__ slot_w,
    const int* __restrict__ meta, ushort* __restrict__ Hout,
    float* __restrict__ y) {
  constexpr int Kd = (GEMM == 1) ? Dn : FFn;
  constexpr int Nd = (GEMM == 1) ? FFn : Dn;
  const int e = blockIdx.z;
  const int cnt = meta[e];
  const int m0 = blockIdx.y * 128;
  if (m0 >= cnt) return;
  const int base = meta[8 + e];
  const int n0 = blockIdx.x * 128;
  const float* We = Wg + (size_t)e * Kd * Nd;

  __shared__ ushort Ah[128 * 32];
  __shared__ ushort Al[128 * 32];   // unused (dead) for GEMM2
  __shared__ ushort Bh[128 * 32];
  __shared__ ushort Bl[128 * 32];
  __shared__ int srow[128];

  const int tid = threadIdx.x;
  if (tid < 128) {
    const int m = min(m0 + tid, cnt - 1);
    srow[tid] = (GEMM == 1) ? slot_token[base + m] : (base + m);
  }
  __syncthreads();

  // staging roles
  const int sm = tid >> 1, skh = tid & 1;         // A: row, k-half(16)
  const int rsrow = srow[sm];
  const float*  arowf = Xf + (size_t)rsrow * Kd;  // GEMM1
  const ushort* arowh = Hb + (size_t)rsrow * Kd;  // GEMM2
  const int bn = tid & 127, bkh = tid >> 7;       // B: col(n), k-half(16)

  // compute roles (4 waves, 2x2 of 64x64)
  const int wv = tid >> 6, ln = tid & 63;
  const int wm = (wv & 1) * 64, wn = (wv >> 1) * 64;
  const int lrow = ln & 15, kg = ln >> 4;

  f32x4 acc[4][4];
#pragma unroll
  for (int i = 0; i < 4; ++i)
#pragma unroll
    for (int j = 0; j < 4; ++j) acc[i][j] = (f32x4){0.f, 0.f, 0.f, 0.f};

  union U8 { ushort u[8]; uint4 q; };

  for (int k0 = 0; k0 < Kd; k0 += 32) {
    __syncthreads();  // prior fragment reads done before overwrite
    // ---- stage A ----
    {
      const int b0 = ((skh * 2 + 0) ^ ((sm >> 1) & 3)) << 3;
      const int b1 = ((skh * 2 + 1) ^ ((sm >> 1) & 3)) << 3;
      if (GEMM == 1) {
        const float* ap = arowf + k0 + skh * 16;
        float v[16];
#pragma unroll
        for (int i = 0; i < 4; ++i) {
          const float4 f = ((const float4*)ap)[i];
          v[i * 4 + 0] = f.x; v[i * 4 + 1] = f.y;
          v[i * 4 + 2] = f.z; v[i * 4 + 3] = f.w;
        }
        U8 h0, h1, l0, l1;
#pragma unroll
        for (int j = 0; j < 8; ++j) {
          unsigned u = __float_as_uint(v[j]);
          h0.u[j] = (ushort)(u >> 16);
          l0.u[j] = (ushort)(__float_as_uint(v[j] - __uint_as_float(u & 0xffff0000u)) >> 16);
          u = __float_as_uint(v[8 + j]);
          h1.u[j] = (ushort)(u >> 16);
          l1.u[j] = (ushort)(__float_as_uint(v[8 + j] - __uint_as_float(u & 0xffff0000u)) >> 16);
        }
        *(uint4*)&Ah[sm * 32 + b0] = h0.q;
        *(uint4*)&Ah[sm * 32 + b1] = h1.q;
        *(uint4*)&Al[sm * 32 + b0] = l0.q;
        *(uint4*)&Al[sm * 32 + b1] = l1.q;
      } else {
        const ushort* hp = arowh + k0 + skh * 16;
        *(uint4*)&Ah[sm * 32 + b0] = ((const uint4*)hp)[0];
        *(uint4*)&Ah[sm * 32 + b1] = ((const uint4*)hp)[1];
      }
    }
    // ---- stage B (transpose fp32 W[k][n] -> split-bf16 [n][k]) ----
    {
      const float* bp = We + (size_t)(k0 + bkh * 16) * Nd + n0 + bn;
      float v[16];
#pragma unroll
      for (int j = 0; j < 16; ++j) v[j] = bp[(size_t)j * Nd];
      U8 h0, h1, l0, l1;
#pragma unroll
      for (int j = 0; j < 8; ++j) {
        unsigned u = __float_as_uint(v[j]);
        h0.u[j] = (ushort)(u >> 16);
        l0.u[j] = (ushort)(__float_as_uint(v[j] - __uint_as_float(u & 0xffff0000u)) >> 16);
        u = __float_as_uint(v[8 + j]);
        h1.u[j] = (ushort)(u >> 16);
        l1.u[j] = (ushort)(__float_as_uint(v[8 + j] - __uint_as_float(u & 0xffff0000u)) >> 16);
      }
      const int b0 = ((bkh * 2 + 0) ^ ((bn >> 1) & 3)) << 3;
      const int b1 = ((bkh * 2 + 1) ^ ((bn >> 1) & 3)) << 3;
      *(uint4*)&Bh[bn * 32 + b0] = h0.q;
      *(uint4*)&Bh[bn * 32 + b1] = h1.q;
      *(uint4*)&Bl[bn * 32 + b0] = l0.q;
      *(uint4*)&Bl[bn * 32 + b1] = l1.q;
    }
    __syncthreads();
    // ---- fragments + MFMA ----
    bf16x8 af[4], alf[4], bhf[4], blf[4];
#pragma unroll
    for (int f = 0; f < 4; ++f) {
      const int ra = wm + f * 16 + lrow;
      const int ia = ra * 32 + ((kg ^ ((ra >> 1) & 3)) << 3);
      af[f] = *(const bf16x8*)&Ah[ia];
      if (GEMM == 1) alf[f] = *(const bf16x8*)&Al[ia];
      const int rb = wn + f * 16 + lrow;
      const int ib = rb * 32 + ((kg ^ ((rb >> 1) & 3)) << 3);
      bhf[f] = *(const bf16x8*)&Bh[ib];
      blf[f] = *(const bf16x8*)&Bl[ib];
    }
#pragma unroll
    for (int fm = 0; fm < 4; ++fm)
#pragma unroll
      for (int fn = 0; fn < 4; ++fn) {
        acc[fm][fn] = __builtin_amdgcn_mfma_f32_16x16x32_bf16(af[fm], bhf[fn], acc[fm][fn], 0, 0, 0);
        acc[fm][fn] = __builtin_amdgcn_mfma_f32_16x16x32_bf16(af[fm], blf[fn], acc[fm][fn], 0, 0, 0);
        if (GEMM == 1)
          acc[fm][fn] = __builtin_amdgcn_mfma_f32_16x16x32_bf16(alf[fm], bhf[fn], acc[fm][fn], 0, 0, 0);
      }
  }

  float bv[4];
#pragma unroll
  for (int fn = 0; fn < 4; ++fn)
    bv[fn] = bias[(size_t)e * Nd + n0 + wn + fn * 16 + lrow];

#pragma unroll
  for (int fm = 0; fm < 4; ++fm)
#pragma unroll
    for (int j = 0; j < 4; ++j) {
      const int m = m0 + wm + fm * 16 + kg * 4 + j;  // C/D: row=(lane>>4)*4+reg
      if (m < cnt) {
        if (GEMM == 1) {
          ushort* hr = Hout + (size_t)(base + m) * FFn + n0 + wn;
#pragma unroll
          for (int fn = 0; fn < 4; ++fn)
            hr[fn * 16 + lrow] = f2bf(fmaxf(acc[fm][fn][j] + bv[fn], 0.f));
        } else {
          const int t = slot_token[base + m];
          const float w = slot_w[base + m];
          float* yr = y + (size_t)t * Dn + n0 + wn;
#pragma unroll
          for (int fn = 0; fn < 4; ++fn)
            atomicAdd(yr + fn * 16 + lrow, w * (acc[fm][fn][j] + bv[fn]));
        }
      }
    }
}

// ------------------------------------- fp32/bf16 fallback (small-ws path) ---
__device__ inline void load8f(const float* p, float* v) {
  const float4 a = ((const float4*)p)[0];
  const float4 b = ((const float4*)p)[1];
  v[0] = a.x; v[1] = a.y; v[2] = a.z; v[3] = a.w;
  v[4] = b.x; v[5] = b.y; v[6] = b.z; v[7] = b.w;
}
__device__ inline void load8h(const __hip_bfloat16* p, float* v) {
  const uint4 r = *(const uint4*)p;
  const unsigned short* s = (const unsigned short*)&r;
#pragma unroll
  for (int j = 0; j < 8; ++j) v[j] = __uint_as_float(((unsigned)s[j]) << 16);
}

__global__ __launch_bounds__(256) void ffn1_kernel(
    const float* __restrict__ X, const float* __restrict__ W1,
    const float* __restrict__ b1, const int* __restrict__ slot_token,
    const int* __restrict__ meta, __hip_bfloat16* __restrict__ hmid) {
  const int e = blockIdx.z;
  const int cnt = meta[e];
  const int m0 = blockIdx.y * 64;
  if (m0 >= cnt) return;
  const int base = meta[8 + e];
  const int n0 = blockIdx.x * 64;
  __shared__ float As[32][64];
  __shared__ float Bs[32][64];
  const int tid = threadIdx.x;
  const int arow = tid >> 2, ak0 = (tid & 3) * 8;
  const int tok = slot_token[base + min(m0 + arow, cnt - 1)];
  const float* xrow = X + (size_t)tok * Dn;
  const int bkk = tid >> 3, bc0 = (tid & 7) * 8;
  const float* wrow = W1 + (size_t)e * Dn * FFn + n0;
  const int tm = (tid >> 4) << 2, tn = (tid & 15) << 2;
  float acc[4][4] = {};
  for (int k0 = 0; k0 < Dn; k0 += 32) {
    float av[8], bv[8];
    load8f(xrow + k0 + ak0, av);
    load8f(wrow + (size_t)(k0 + bkk) * FFn + bc0, bv);
    __syncthreads();
#pragma unroll
    for (int u = 0; u < 8; ++u) As[ak0 + u][arow] = av[u];
#pragma unroll
    for (int u = 0; u < 8; ++u) Bs[bkk][bc0 + u] = bv[u];
    __syncthreads();
#pragma unroll
    for (int kk = 0; kk < 32; ++kk) {
      float a[4], b[4];
#pragma unroll
      for (int i = 0; i < 4; ++i) a[i] = As[kk][tm + i];
#pragma unroll
      for (int j = 0; j < 4; ++j) b[j] = Bs[kk][tn + j];
#pragma unroll
      for (int i = 0; i < 4; ++i)
#pragma unroll
        for (int j = 0; j < 4; ++j) acc[i][j] = fmaf(a[i], b[j], acc[i][j]);
    }
  }
  const float* bb = b1 + (size_t)e * FFn + n0;
#pragma unroll
  for (int i = 0; i < 4; ++i) {
    const int m = m0 + tm + i;
    if (m < cnt) {
      __hip_bfloat16* hr = hmid + (size_t)(base + m) * FFn + n0 + tn;
#pragma unroll
      for (int j = 0; j < 4; ++j)
        hr[j] = __hip_bfloat16(fmaxf(acc[i][j] + bb[tn + j], 0.f));
    }
  }
}

__global__ __launch_bounds__(256) void ffn2_kernel(
    const __hip_bfloat16* __restrict__ hmid, const float* __restrict__ W2,
    const float* __restrict__ b2, const int* __restrict__ slot_token,
    const float* __restrict__ slot_w, const int* __restrict__ meta,
    float* __restrict__ y) {
  const int e = blockIdx.z;
  const int cnt = meta[e];
  const int m0 = blockIdx.y * 64;
  if (m0 >= cnt) return;
  const int base = meta[8 + e];
  const int n0 = blockIdx.x * 64;
  __shared__ float As[32][64];
  __shared__ float Bs[32][64];
  const int tid = threadIdx.x;
  const int arow = tid >> 2, ak0 = (tid & 3) * 8;
  const __hip_bfloat16* hrow = hmid + (size_t)(base + min(m0 + arow, cnt - 1)) * FFn;
  const int bkk = tid >> 3, bc0 = (tid & 7) * 8;
  const float* wrow = W2 + (size_t)e * FFn * Dn + n0;
  const int tm = (tid >> 4) << 2, tn = (tid & 15) << 2;
  float acc[4][4] = {};
  for (int k0 = 0; k0 < FFn; k0 += 32) {
    float av[8], bv[8];
    load8h(hrow + k0 + ak0, av);
    load8f(wrow + (size_t)(k0 + bkk) * Dn + bc0, bv);
    __syncthreads();
#pragma unroll
    for (int u = 0; u < 8; ++u) As[ak0 + u][arow] = av[u];
#pragma unroll
    for (int u = 0; u < 8; ++u) Bs[bkk][bc0 + u] = bv[u];
    __syncthreads();
#pragma unroll
    for (int kk = 0; kk < 32; ++kk) {
      float a[4], b[4];
#pragma unroll
      for (int i = 0; i < 4; ++i) a[i] = As[kk][tm + i];
#pragma unroll
      for (int j = 0; j < 4; ++j) b[j] = Bs[kk][tn + j];
#pragma unroll
      for (int i = 0; i < 4; ++i)
#pragma unroll
        for (int j = 0; j < 4; ++j) acc[i][j] = fmaf(a[i], b[j], acc[i][j]);
    }
  }
  const float* bb = b2 + (size_t)e * Dn + n0;
#pragma unroll
  for (int i = 0; i < 4; ++i) {
    const int m = m0 + tm + i;
    if (m < cnt) {
      const int t = slot_token[base + m];
      const float w = slot_w[base + m];
      float* yr = y + (size_t)t * Dn + n0 + tn;
#pragma unroll
      for (int j = 0; j < 4; ++j)
        atomicAdd(&yr[j], w * (acc[i][j] + bb[tn + j]));
    }
  }
}

// ---------------------------------------------------------------- launch ----
extern "C" void kernel_launch(void* const* d_in, const int* in_sizes, int n_in,
                              void* d_out, int out_size, void* d_ws, size_t ws_size,
                              hipStream_t stream) {
  const float* h  = (const float*)d_in[0];
  const float* gw = (const float*)d_in[1];
  const float* gb = (const float*)d_in[2];
  const float* W1 = (const float*)d_in[3];
  const float* b1 = (const float*)d_in[4];
  const float* W2 = (const float*)d_in[5];
  const float* b2 = (const float*)d_in[6];
  float* y = (float*)d_out;

  char* ws = (char*)d_ws;
  size_t off = 0;
  auto carve = [&](size_t bytes) -> char* {
    char* p = ws + off;
    off = (off + bytes + 255) & ~(size_t)255;
    return p;
  };
  int*    tidx       = (int*)carve((size_t)Tn * 2 * 4);
  float*  tprob      = (float*)carve((size_t)Tn * 2 * 4);
  int*    slot_token = (int*)carve((size_t)MAXROWS * 4);
  float*  slot_w     = (float*)carve((size_t)MAXROWS * 4);
  int*    meta       = (int*)carve(256);
  const size_t small_end = off;

  hipMemsetAsync(d_out, 0, (size_t)Tn * Dn * sizeof(float), stream);
  gate_kernel<<<Tn / 4, 256, 0, stream>>>(h, gw, gb, tidx, tprob);
  route_kernel<<<1, 1024, 0, stream>>>(tidx, tprob, slot_token, slot_w, meta);

  // ---- MFMA path: ws needs only H (bf16) -> 134.5 MB, proven to fit ----
  const size_t hplane = (size_t)MAXROWS * FFn * 2;
  const size_t need_mfma = small_end + hplane;

  if (ws_size >= need_mfma) {
    ushort* H = (ushort*)carve(hplane);
    const dim3 g1(FFn / 128, (2 * CAPn + 127) / 128, En);  // (32, 40, 8)
    const dim3 g2(Dn / 128, (2 * CAPn + 127) / 128, En);   // (8, 40, 8)
    mfma_ffn<1><<<g1, 256, 0, stream>>>(h, nullptr, W1, b1, slot_token,
                                        slot_w, meta, H, nullptr);
    mfma_ffn<2><<<g2, 256, 0, stream>>>(nullptr, H, W2, b2, slot_token,
                                        slot_w, meta, nullptr, y);
    return;
  }

  // ---- fallback (proven-pass round 4) ----
  __hip_bfloat16* hmid = (__hip_bfloat16*)(ws + small_end);
  const dim3 f1(FFn / 64, (2 * CAPn + 63) / 64, En);
  const dim3 f2(Dn / 64, (2 * CAPn + 63) / 64, En);
  ffn1_kernel<<<f1, 256, 0, stream>>>(h, W1, b1, slot_token, meta, hmid);
  ffn2_kernel<<<f2, 256, 0, stream>>>(hmid, W2, b2, slot_token, slot_w, meta, y);
}